// Round 16
// baseline (131.222 us; speedup 1.0000x reference)
//
#include <hip/hip_runtime.h>

#define Bq 2
#define Lq 2048
#define Dq 1024
#define Hq 16
#define HDq 64

typedef _Float16 f16;
typedef _Float16 f16x8 __attribute__((ext_vector_type(8)));
typedef _Float16 f16x4 __attribute__((ext_vector_type(4)));
typedef __fp16 hf16x2 __attribute__((ext_vector_type(2)));
typedef float f32x4 __attribute__((ext_vector_type(4)));

__device__ __forceinline__ void gload_lds16(const void* g, void* l) {
    __builtin_amdgcn_global_load_lds(
        (const __attribute__((address_space(1))) unsigned int*)g,
        (__attribute__((address_space(3))) unsigned int*)l, 16, 0, 0);
}

__device__ __forceinline__ int pk2(float a, float b) {
    hf16x2 v = __builtin_amdgcn_cvt_pkrtz(a, b);
    return __builtin_bit_cast(int, v);
}

// ---------------- fp32 -> fp16 conversion ------------------------------------
__global__ __launch_bounds__(256) void convert_kernel(
    const float* __restrict__ x,
    const float* __restrict__ wq, const float* __restrict__ wk, const float* __restrict__ wv,
    f16* __restrict__ x_h, f16* __restrict__ wq_h, f16* __restrict__ wk_h, f16* __restrict__ wv_h)
{
    const int NX = Bq*Lq*Dq;
    const int NW = Dq*Dq;
    const int total4 = (NX + 3*NW) / 4;
    for (int i = blockIdx.x*blockDim.x + threadIdx.x; i < total4;
         i += gridDim.x*blockDim.x) {
        int e = i * 4;
        const float* src; f16* dst; int off;
        if (e < NX) { src = x; dst = x_h; off = e; }
        else {
            int t = e - NX; int w = t >> 20; off = t & (NW-1);
            src = (w==0) ? wq : (w==1) ? wk : wv;
            dst = (w==0) ? wq_h : (w==1) ? wk_h : wv_h;
        }
        float4 v = *reinterpret_cast<const float4*>(src + off);
        f16x4 hv; hv.x=(f16)v.x; hv.y=(f16)v.y; hv.z=(f16)v.z; hv.w=(f16)v.w;
        *reinterpret_cast<f16x4*>(dst + off) = hv;
    }
}

// ------- fused: QKV projection (id<768) + quantum transpose (id>=768) --------
#define GBM 128
#define GBN 128
#define GBK 32

__global__ __launch_bounds__(256) void qkv_qm_fused_kernel(
    const f16* __restrict__ x_h,
    const f16* __restrict__ wq_h, const f16* __restrict__ wk_h, const f16* __restrict__ wv_h,
    const float* __restrict__ quantum,
    f16* __restrict__ q_h, f16* __restrict__ k_h, f16* __restrict__ vT_h,
    f16* __restrict__ qm_pre)
{
    __shared__ __align__(16) char smem[16384];
    const int tid = threadIdx.x;
    const int id  = blockIdx.x;

    if (id < 768) {
        // ---------------- GEMM block ----------------
        f16* As = (f16*)smem;
        f16* Bs = (f16*)(smem + 8192);
        const int lane = tid & 63;
        const int wave = tid >> 6;
        const int wr = wave >> 1, wc = wave & 1;
        const int l15 = lane & 15, l4 = lane >> 4;
        const int n0 = (id & 7) * GBN;
        const int m0 = ((id >> 3) & 31) * GBM;
        const int z  = id >> 8;
        const f16* W = (z==0) ? wq_h : (z==1) ? wk_h : wv_h;
        const int sslot = tid & 3;

        f32x4 acc[4][4];
        #pragma unroll
        for (int i=0;i<4;++i)
            #pragma unroll
            for (int j=0;j<4;++j) acc[i][j] = f32x4{0.f,0.f,0.f,0.f};

        for (int kt = 0; kt < Dq; kt += GBK) {
            __syncthreads();
            #pragma unroll
            for (int j = 0; j < 2; ++j) {
                int slotIdx = tid + j*256;
                int row = slotIdx >> 2;
                gload_lds16(x_h + (size_t)(m0+row)*Dq + kt + sslot*8,
                            (char*)As + slotIdx*16);
                gload_lds16(W   + (size_t)(n0+row)*Dq + kt + sslot*8,
                            (char*)Bs + slotIdx*16);
            }
            __syncthreads();

            f16x8 a[4], b[4];
            #pragma unroll
            for (int m=0;m<4;++m) {
                int row = wr*64 + m*16 + l15;
                a[m] = *reinterpret_cast<const f16x8*>((const char*)As + row*64 + l4*16);
            }
            #pragma unroll
            for (int n=0;n<4;++n) {
                int row = wc*64 + n*16 + l15;
                b[n] = *reinterpret_cast<const f16x8*>((const char*)Bs + row*64 + l4*16);
            }
            #pragma unroll
            for (int m=0;m<4;++m)
                #pragma unroll
                for (int n=0;n<4;++n)
                    acc[m][n] = __builtin_amdgcn_mfma_f32_16x16x32_f16(a[m], b[n], acc[m][n], 0,0,0);
        }

        #pragma unroll
        for (int m=0;m<4;++m) {
            #pragma unroll
            for (int r=0;r<4;++r) {
                int grow = m0 + wr*64 + m*16 + l4*4 + r;
                int b_   = grow >> 11;
                int lrow = grow & (Lq-1);
                #pragma unroll
                for (int n=0;n<4;++n) {
                    int gcol = n0 + wc*64 + n*16 + l15;
                    int h = gcol >> 6, d = gcol & 63;
                    int bh = b_*Hq + h;
                    f16 val = (f16)acc[m][n][r];
                    if (z==0)      q_h[((size_t)bh*Lq + lrow)*HDq + d] = val;
                    else if (z==1) k_h[((size_t)bh*Lq + lrow)*HDq + d] = val;
                    else           vT_h[((size_t)bh*HDq + d)*Lq + lrow] = val;
                }
            }
        }
    } else {
        // ------- quantum transpose: 16-q-row chunks, 16x16-C-fragment order ---
        // chunk (b, kt64, qt16): 1024 f16; addr = frag*512 + lane*8 + e, value =
        // quantum[b][qt16*16 + (lane&15)][kt*64 + 16*(frag*2+(e>>2)) + (lane>>4)*4 + (e&3)]
        float (*qs)[65] = (float(*)[65])smem;
        const int q  = id - 768;
        const int qt32 = q & 63;
        const int kt = (q >> 6) & 31;
        const int b  = q >> 11;
        const float* base = quantum + ((size_t)b*Lq + qt32*32)*Lq + kt*64;
        #pragma unroll
        for (int i=0;i<2;++i) {
            int idx = tid + i*256;
            int r = idx >> 4, c = (idx & 15)*4;
            float4 v = *reinterpret_cast<const float4*>(base + (size_t)r*Lq + c);
            qs[r][c]=v.x; qs[r][c+1]=v.y; qs[r][c+2]=v.z; qs[r][c+3]=v.w;
        }
        __syncthreads();
        const int seg = tid >> 6;              // 0..3: half(qt16) + frag
        const int half = seg >> 1, frag = seg & 1;
        const int lane = tid & 63, l15 = lane & 15, l4 = lane >> 4;
        f16x8 u;
        #pragma unroll
        for (int e=0;e<8;++e) {
            int key = 16*(frag*2 + (e>>2)) + l4*4 + (e&3);
            u[e] = (f16)qs[half*16 + l15][key];
        }
        f16* outp = qm_pre + (((size_t)b*32 + kt)*128 + qt32*2 + half)*1024
                    + frag*512 + lane*8;
        *reinterpret_cast<f16x8*>(outp) = u;
    }
}

// ---- flash attention: 8 waves x 16 q-rows, 4 waves/SIMD, 16x16 MFMAs --------
__global__ __launch_bounds__(512, 4) void attn8_kernel(
    const f16* __restrict__ q_h, const f16* __restrict__ k_h, const f16* __restrict__ vT_h,
    const f16* __restrict__ qm_pre, const float* __restrict__ scale,
    float* __restrict__ out)
{
    __shared__ __align__(16) char lds[65536];   // 4 quarters x [K 8KB | V 8KB]

    const int tid  = threadIdx.x;
    const int lane = tid & 63;
    const int wave = tid >> 6;          // 0..7
    const int l15  = lane & 15;
    const int l4   = lane >> 4;         // 0..3
    const int bh = blockIdx.x;
    const int qb = blockIdx.y;
    const int b_ = bh >> 4, h = bh & 15;
    const int qW = qb*128 + wave*16;    // this wave's 16 q-rows
    const int qt16 = qb*8 + wave;
    const float sc = scale[h];
    const float c1 = 0.125f * sc * 1.44269504f;
    const float c2 = sc * 1.44269504f;

    const f16* kbase = k_h  + (size_t)bh*Lq*HDq;
    const f16* vbase = vT_h + (size_t)bh*HDq*Lq;

    // Q fragments (B-operand 16x16x32: col=q=l15, k = d = l4*8+e (+32s))
    f16x8 qf[2];
    {
        const f16* qb_ = q_h + ((size_t)bh*Lq + qW + l15)*HDq + l4*8;
        qf[0] = *reinterpret_cast<const f16x8*>(qb_);
        qf[1] = *reinterpret_cast<const f16x8*>(qb_ + 32);
    }

    f32x4 o[4];
    #pragma unroll
    for (int dt=0;dt<4;++dt) o[dt] = f32x4{0.f,0.f,0.f,0.f};
    float m_run = -1e30f, s_run = 0.f;   // per-lane: q = l15, partial over l4 groups

    // tile t (0..31) lives in quarter ((t>>1)&1)*2 + (t&1)
    auto QTR = [](int t) { return ((t >> 1) & 1)*2 + (t & 1); };

    auto STAGE = [&](int t) {
        const int k0 = t*64;
        char* LK = lds + QTR(t)*16384;
        char* LV = LK + 8192;
        int row = tid >> 3, slot = tid & 7;   // 512 thr = 64 rows x 8 slots
        int ss = slot ^ (row & 7);
        gload_lds16(kbase + (size_t)(k0+row)*HDq + ss*8, LK + tid*16);
        gload_lds16(vbase + (size_t)row*Lq + k0 + ss*8,  LV + tid*16);
    };

    auto QMLOAD = [&](int t, f16x8 (&qm)[2]) {
        const f16* qmb = qm_pre + (((size_t)b_*32 + t)*128 + qt16)*1024 + lane*8;
        qm[0] = *reinterpret_cast<const f16x8*>(qmb);
        qm[1] = *reinterpret_cast<const f16x8*>(qmb + 512);
    };

    auto TILE = [&](int t, f16x8 (&qm)[2]) {
        const char* LK = lds + QTR(t)*16384;
        const char* LV = LK + 8192;

        // S^T tiles: st[tt] = K(16 keys) . Q^T, C: col=q=l15, row=key=l4*4+r
        f32x4 st[4];
        __builtin_amdgcn_s_setprio(1);
        #pragma unroll
        for (int tt=0;tt<4;++tt) {
            st[tt] = f32x4{0.f,0.f,0.f,0.f};
            #pragma unroll
            for (int s=0;s<2;++s) {
                int krow = tt*16 + l15;
                f16x8 ka = *reinterpret_cast<const f16x8*>(
                    LK + (krow<<7) + (((s*4 + l4) ^ (krow&7))<<4));
                st[tt] = __builtin_amdgcn_mfma_f32_16x16x32_f16(ka, qf[s], st[tt], 0,0,0);
            }
        }
        __builtin_amdgcn_s_setprio(0);

        // logits (base-2): lg[tt*4+r], key = 16tt + l4*4 + r, q = l15
        float lg[16];
        #pragma unroll
        for (int f=0;f<2;++f)
            #pragma unroll
            for (int e=0;e<8;++e) {
                int tt = f*2 + (e>>2), r = e&3;
                lg[tt*4+r] = st[tt][r]*c1 + (float)qm[f][e]*c2;
            }

        // row max: in-lane 16 -> cross-group (xor 16, 32)
        float tm[8];
        #pragma unroll
        for (int r=0;r<8;++r) tm[r] = fmaxf(lg[r], lg[r+8]);
        #pragma unroll
        for (int w=4; w>0; w>>=1)
            #pragma unroll
            for (int r=0;r<w;++r) tm[r] = fmaxf(tm[r], tm[r+w]);
        float tmax = tm[0];
        tmax = fmaxf(tmax, __shfl_xor(tmax, 16));
        tmax = fmaxf(tmax, __shfl_xor(tmax, 32));

        if (!__all(tmax <= m_run + 8.f)) {
            float m_new = fmaxf(m_run, tmax);
            float corr = __builtin_amdgcn_exp2f(m_run - m_new);
            m_run = m_new;
            s_run *= corr;
            #pragma unroll
            for (int dt=0;dt<4;++dt) o[dt] *= corr;
        }

        // P = 2^(lg - m); partial sum (own keys only)
        float p[16];
        #pragma unroll
        for (int r=0;r<16;++r) p[r] = __builtin_amdgcn_exp2f(lg[r] - m_run);
        float sm[8];
        #pragma unroll
        for (int r=0;r<8;++r) sm[r] = p[r] + p[r+8];
        #pragma unroll
        for (int w=4; w>0; w>>=1)
            #pragma unroll
            for (int r=0;r<w;++r) sm[r] += sm[r+w];
        s_run += sm[0];

        // PV: O^T += V^T . P^T via 16x16x16 (B k-mapping == P C-layout: in-lane pack)
        __builtin_amdgcn_s_setprio(1);
        #pragma unroll
        for (int tt=0;tt<4;++tt) {
            union { int w[2]; f16x4 v; } u;
            u.w[0] = pk2(p[tt*4+0], p[tt*4+1]);
            u.w[1] = pk2(p[tt*4+2], p[tt*4+3]);
            #pragma unroll
            for (int dt=0;dt<4;++dt) {
                int d = dt*16 + l15;
                f16x4 va = *reinterpret_cast<const f16x4*>(
                    LV + (d<<7) + (((tt*2 + (l4>>1)) ^ (d&7))<<4) + (l4&1)*8);
                o[dt] = __builtin_amdgcn_mfma_f32_16x16x16f16(va, u.v, o[dt], 0,0,0);
            }
        }
        __builtin_amdgcn_s_setprio(0);
    };

    f16x8 qmA[2], qmB[2];

    // prologue: stage epoch-0 tiles, drain, barrier
    STAGE(0); STAGE(1);
    asm volatile("s_waitcnt vmcnt(0)" ::: "memory");
    __builtin_amdgcn_s_barrier();

    // epochs: QM first (compiler waits vmcnt(4) for them, stages stay in flight),
    // stage next pair, compute both tiles, drain stages (full-epoch lead), barrier.
    for (int e = 0; e < 15; ++e) {
        QMLOAD(2*e, qmA); QMLOAD(2*e+1, qmB);
        STAGE(2*e+2); STAGE(2*e+3);
        TILE(2*e,   qmA);
        TILE(2*e+1, qmB);
        asm volatile("s_waitcnt vmcnt(0)" ::: "memory");
        __builtin_amdgcn_s_barrier();
    }
    QMLOAD(30, qmA); QMLOAD(31, qmB);
    TILE(30, qmA);
    TILE(31, qmB);

    // epilogue: full row-sum (4 groups), normalize, write O^T
    float s_tot = s_run;
    s_tot += __shfl_xor(s_tot, 16);
    s_tot += __shfl_xor(s_tot, 32);
    float inv = 1.0f / s_tot;
    float* ob = out + ((size_t)b_*Lq + qW + l15)*Dq + h*HDq;
    #pragma unroll
    for (int dt=0;dt<4;++dt)
        #pragma unroll
        for (int r=0;r<4;++r)
            ob[dt*16 + l4*4 + r] = o[dt][r]*inv;
}

extern "C" void kernel_launch(void* const* d_in, const int* in_sizes, int n_in,
                              void* d_out, int out_size, void* d_ws, size_t ws_size,
                              hipStream_t stream) {
    const float* x       = (const float*)d_in[0];
    const float* quantum = (const float*)d_in[1];
    const float* wq      = (const float*)d_in[2];
    const float* wk      = (const float*)d_in[3];
    const float* wv      = (const float*)d_in[4];
    const float* scale   = (const float*)d_in[5];
    float* out = (float*)d_out;

    f16* ws     = (f16*)d_ws;
    f16* x_h    = ws;
    f16* wq_h   = ws + 4194304;
    f16* wk_h   = ws + 5242880;
    f16* wv_h   = ws + 6291456;
    f16* q_h    = ws + 7340032;
    f16* k_h    = ws + 11534336;
    f16* vT_h   = ws + 15728640;
    f16* qm_pre = ws + 19922944;

    convert_kernel<<<1024, 256, 0, stream>>>(x, wq, wk, wv, x_h, wq_h, wk_h, wv_h);

    qkv_qm_fused_kernel<<<4864, 256, 0, stream>>>(
        x_h, wq_h, wk_h, wv_h, quantum, q_h, k_h, vT_h, qm_pre);

    dim3 g2(Bq*Hq, Lq/128);
    attn8_kernel<<<g2, 512, 0, stream>>>(q_h, k_h, vT_h, qm_pre, scale, out);
}

// Round 17
// 127.155 us; speedup vs baseline: 1.0320x; 1.0320x over previous
//
#include <hip/hip_runtime.h>

#define Bq 2
#define Lq 2048
#define Dq 1024
#define Hq 16
#define HDq 64

typedef _Float16 f16;
typedef _Float16 f16x8 __attribute__((ext_vector_type(8)));
typedef _Float16 f16x4 __attribute__((ext_vector_type(4)));
typedef __fp16 hf16x2 __attribute__((ext_vector_type(2)));
typedef float f32x4 __attribute__((ext_vector_type(4)));
typedef float f32x16 __attribute__((ext_vector_type(16)));

__device__ __forceinline__ void gload_lds16(const void* g, void* l) {
    __builtin_amdgcn_global_load_lds(
        (const __attribute__((address_space(1))) unsigned int*)g,
        (__attribute__((address_space(3))) unsigned int*)l, 16, 0, 0);
}

__device__ __forceinline__ void swap32(int& a, int& b) {
    asm volatile("v_permlane32_swap_b32 %0, %1" : "+v"(a), "+v"(b));
}

__device__ __forceinline__ int pk2(float a, float b) {
    hf16x2 v = __builtin_amdgcn_cvt_pkrtz(a, b);
    return __builtin_bit_cast(int, v);
}

// ---------------- fp32 -> fp16 conversion ------------------------------------
__global__ __launch_bounds__(256) void convert_kernel(
    const float* __restrict__ x,
    const float* __restrict__ wq, const float* __restrict__ wk, const float* __restrict__ wv,
    f16* __restrict__ x_h, f16* __restrict__ wq_h, f16* __restrict__ wk_h, f16* __restrict__ wv_h)
{
    const int NX = Bq*Lq*Dq;
    const int NW = Dq*Dq;
    const int total4 = (NX + 3*NW) / 4;
    for (int i = blockIdx.x*blockDim.x + threadIdx.x; i < total4;
         i += gridDim.x*blockDim.x) {
        int e = i * 4;
        const float* src; f16* dst; int off;
        if (e < NX) { src = x; dst = x_h; off = e; }
        else {
            int t = e - NX; int w = t >> 20; off = t & (NW-1);
            src = (w==0) ? wq : (w==1) ? wk : wv;
            dst = (w==0) ? wq_h : (w==1) ? wk_h : wv_h;
        }
        float4 v = *reinterpret_cast<const float4*>(src + off);
        f16x4 hv; hv.x=(f16)v.x; hv.y=(f16)v.y; hv.z=(f16)v.z; hv.w=(f16)v.w;
        *reinterpret_cast<f16x4*>(dst + off) = hv;
    }
}

// ------- fused: QKV projection (id<768) + quantum transpose (id>=768) --------
#define GBM 128
#define GBN 128
#define GBK 32

__global__ __launch_bounds__(256) void qkv_qm_fused_kernel(
    const f16* __restrict__ x_h,
    const f16* __restrict__ wq_h, const f16* __restrict__ wk_h, const f16* __restrict__ wv_h,
    const float* __restrict__ quantum,
    f16* __restrict__ q_h, f16* __restrict__ k_h, f16* __restrict__ vT_h,
    f16* __restrict__ qm_pre)
{
    __shared__ __align__(16) char smem[16384];
    const int tid = threadIdx.x;
    const int id  = blockIdx.x;

    if (id < 768) {
        // ---------------- GEMM block ----------------
        f16* As = (f16*)smem;
        f16* Bs = (f16*)(smem + 8192);
        const int lane = tid & 63;
        const int wave = tid >> 6;
        const int wr = wave >> 1, wc = wave & 1;
        const int l15 = lane & 15, l4 = lane >> 4;
        const int n0 = (id & 7) * GBN;
        const int m0 = ((id >> 3) & 31) * GBM;
        const int z  = id >> 8;
        const f16* W = (z==0) ? wq_h : (z==1) ? wk_h : wv_h;
        const int sslot = tid & 3;

        f32x4 acc[4][4];
        #pragma unroll
        for (int i=0;i<4;++i)
            #pragma unroll
            for (int j=0;j<4;++j) acc[i][j] = f32x4{0.f,0.f,0.f,0.f};

        for (int kt = 0; kt < Dq; kt += GBK) {
            __syncthreads();
            #pragma unroll
            for (int j = 0; j < 2; ++j) {
                int slotIdx = tid + j*256;
                int row = slotIdx >> 2;
                gload_lds16(x_h + (size_t)(m0+row)*Dq + kt + sslot*8,
                            (char*)As + slotIdx*16);
                gload_lds16(W   + (size_t)(n0+row)*Dq + kt + sslot*8,
                            (char*)Bs + slotIdx*16);
            }
            __syncthreads();

            f16x8 a[4], b[4];
            #pragma unroll
            for (int m=0;m<4;++m) {
                int row = wr*64 + m*16 + l15;
                a[m] = *reinterpret_cast<const f16x8*>((const char*)As + row*64 + l4*16);
            }
            #pragma unroll
            for (int n=0;n<4;++n) {
                int row = wc*64 + n*16 + l15;
                b[n] = *reinterpret_cast<const f16x8*>((const char*)Bs + row*64 + l4*16);
            }
            #pragma unroll
            for (int m=0;m<4;++m)
                #pragma unroll
                for (int n=0;n<4;++n)
                    acc[m][n] = __builtin_amdgcn_mfma_f32_16x16x32_f16(a[m], b[n], acc[m][n], 0,0,0);
        }

        #pragma unroll
        for (int m=0;m<4;++m) {
            #pragma unroll
            for (int r=0;r<4;++r) {
                int grow = m0 + wr*64 + m*16 + l4*4 + r;
                int b_   = grow >> 11;
                int lrow = grow & (Lq-1);
                #pragma unroll
                for (int n=0;n<4;++n) {
                    int gcol = n0 + wc*64 + n*16 + l15;
                    int h = gcol >> 6, d = gcol & 63;
                    int bh = b_*Hq + h;
                    f16 val = (f16)acc[m][n][r];
                    if (z==0)      q_h[((size_t)bh*Lq + lrow)*HDq + d] = val;
                    else if (z==1) k_h[((size_t)bh*Lq + lrow)*HDq + d] = val;
                    else           vT_h[((size_t)bh*HDq + d)*Lq + lrow] = val;
                }
            }
        }
    } else {
        // ---------------- quantum transpose block ----------------
        float (*qs)[64] = (float(*)[64])smem;
        const int q  = id - 768;
        const int qt = q & 63;
        const int kt = (q >> 6) & 31;
        const int b  = q >> 11;
        const float* base = quantum + ((size_t)b*Lq + qt*32)*Lq + kt*64;
        #pragma unroll
        for (int i=0;i<2;++i) {
            int idx = tid + i*256;
            int r = idx >> 4, c = (idx & 15)*4;
            float4 v = *reinterpret_cast<const float4*>(base + (size_t)r*Lq + c);
            qs[r][c]=v.x; qs[r][c+1]=v.y; qs[r][c+2]=v.z; qs[r][c+3]=v.w;
        }
        __syncthreads();
        const int seg = tid >> 6, lane = tid & 63, l31 = lane & 31, hi = lane >> 5;
        f16x8 u;
        #pragma unroll
        for (int e=0;e<8;++e) {
            int key = 16*seg + 8*(e>>2) + 4*hi + (e&3);
            u[e] = (f16)qs[l31][key];
        }
        f16* outp = qm_pre + (((size_t)b*32 + kt)*64 + qt)*2048 + seg*512 + lane*8;
        *reinterpret_cast<f16x8*>(outp) = u;
    }
}

// ---- flash attention: 2-tile software-pipelined epochs (QK,QK,SMPV,SMPV) ----
__global__ __launch_bounds__(256, 2) void attn4_kernel(
    const f16* __restrict__ q_h, const f16* __restrict__ k_h, const f16* __restrict__ vT_h,
    const f16* __restrict__ qm_pre, const float* __restrict__ scale,
    float* __restrict__ out)
{
    __shared__ __align__(16) char lds[65536];   // 4 quarters x [K 8KB | V 8KB]

    const int tid  = threadIdx.x;
    const int lane = tid & 63;
    const int wave = tid >> 6;          // 0..3
    const int l31  = lane & 31;
    const int hi   = lane >> 5;
    const int bh = blockIdx.x;
    const int qb = blockIdx.y;
    const int b_ = bh >> 4, h = bh & 15;
    const int qW = qb*128 + wave*32;
    const int qt = qb*4 + wave;
    const float sc = scale[h];
    const float c1 = 0.125f * sc * 1.44269504f;
    const float c2 = sc * 1.44269504f;

    const f16* kbase = k_h  + (size_t)bh*Lq*HDq;
    const f16* vbase = vT_h + (size_t)bh*HDq*Lq;

    f16x8 qf[4];
    {
        const f16* qb_ = q_h + ((size_t)bh*Lq + qW + l31)*HDq + hi*8;
        #pragma unroll
        for (int ds=0; ds<4; ++ds)
            qf[ds] = *reinterpret_cast<const f16x8*>(qb_ + ds*16);
    }

    f32x16 o0, o1;
    #pragma unroll
    for (int r=0;r<16;++r) { o0[r]=0.f; o1[r]=0.f; }
    float m_run = -1e30f, s_run = 0.f;

    // tile t (0..31) lives in quarter ((t>>1)&1)*2 + (t&1)
    auto QTR = [](int t) { return ((t >> 1) & 1)*2 + (t & 1); };

    auto STAGE = [&](int t) {
        const int k0 = t*64;
        char* LK = lds + QTR(t)*16384;
        char* LV = LK + 8192;
        #pragma unroll
        for (int i=0;i<2;++i) {
            int g = tid + i*256;
            int row = g >> 3, slot = g & 7;
            int ss = slot ^ (row & 7);
            gload_lds16(kbase + (size_t)(k0+row)*HDq + ss*8, LK + g*16);
            gload_lds16(vbase + (size_t)row*Lq + k0 + ss*8,  LV + g*16);
        }
    };

    auto QMLOAD = [&](int t, f16x8 (&qm)[4]) {
        const f16* qmb = qm_pre + (((size_t)b_*32 + t)*64 + qt)*2048 + lane*8;
        #pragma unroll
        for (int s=0;s<4;++s)
            qm[s] = *reinterpret_cast<const f16x8*>(qmb + s*512);
    };

    // QK^T only: st = K Q^T for tile t (no dependence on softmax state)
    auto QK = [&](int t, f32x16 (&st)[2]) {
        const char* LK = lds + QTR(t)*16384;
        __builtin_amdgcn_s_setprio(1);
        #pragma unroll
        for (int kt=0;kt<2;++kt) {
            #pragma unroll
            for (int r=0;r<16;++r) st[kt][r]=0.f;
            #pragma unroll
            for (int ds=0;ds<4;++ds) {
                f16x8 ka = *reinterpret_cast<const f16x8*>(
                    LK + ((kt*32+l31)<<7) + (((ds*2+hi)^(l31&7))<<4));
                st[kt] = __builtin_amdgcn_mfma_f32_32x32x16_f16(ka, qf[ds], st[kt], 0,0,0);
            }
        }
        __builtin_amdgcn_s_setprio(0);
    };

    // softmax + PV for tile t (consumes st, qmc)
    auto SMPV = [&](int t, f32x16 (&st)[2], f16x8 (&qmc)[4]) {
        const char* LV = lds + QTR(t)*16384 + 8192;

        float lg[32];
        #pragma unroll
        for (int s=0;s<4;++s)
            #pragma unroll
            for (int e=0;e<8;++e) {
                int i = s*8 + e;
                float sv = (i < 16) ? st[0][i] : st[1][i-16];
                lg[i] = sv*c1 + (float)qmc[s][e]*c2;
            }

        float tm[16];
        #pragma unroll
        for (int r=0;r<16;++r) tm[r] = fmaxf(lg[r], lg[r+16]);
        #pragma unroll
        for (int w=8; w>0; w>>=1)
            #pragma unroll
            for (int r=0;r<w;++r) tm[r] = fmaxf(tm[r], tm[r+w]);
        float tmax = fmaxf(tm[0], __shfl_xor(tm[0], 32));

        if (!__all(tmax <= m_run + 8.f)) {
            float m_new = fmaxf(m_run, tmax);
            float corr = __builtin_amdgcn_exp2f(m_run - m_new);
            m_run = m_new;
            s_run *= corr;
            #pragma unroll
            for (int r=0;r<16;++r) { o0[r] *= corr; o1[r] *= corr; }
        }

        float p[32];
        #pragma unroll
        for (int r=0;r<32;++r) p[r] = __builtin_amdgcn_exp2f(lg[r] - m_run);
        float sm[16];
        #pragma unroll
        for (int r=0;r<16;++r) sm[r] = p[r] + p[r+16];
        #pragma unroll
        for (int w=8; w>0; w>>=1)
            #pragma unroll
            for (int r=0;r<w;++r) sm[r] += sm[r+w];
        s_run += sm[0];

        f16x8 pb[4];
        #pragma unroll
        for (int ks=0; ks<4; ++ks) {
            int w0 = pk2(p[8*ks+0], p[8*ks+1]);
            int w1 = pk2(p[8*ks+2], p[8*ks+3]);
            int w2 = pk2(p[8*ks+4], p[8*ks+5]);
            int w3 = pk2(p[8*ks+6], p[8*ks+7]);
            swap32(w0, w2);
            swap32(w1, w3);
            union { int w[4]; f16x8 v; } u;
            u.w[0]=w0; u.w[1]=w1; u.w[2]=w2; u.w[3]=w3;
            pb[ks] = u.v;
        }

        __builtin_amdgcn_s_setprio(1);
        #pragma unroll
        for (int ks=0; ks<4; ++ks) {
            f16x8 va0 = *reinterpret_cast<const f16x8*>(
                LV + (l31<<7)        + (((ks*2+hi)^(l31&7))<<4));
            f16x8 va1 = *reinterpret_cast<const f16x8*>(
                LV + ((32+l31)<<7)   + (((ks*2+hi)^(l31&7))<<4));
            o0 = __builtin_amdgcn_mfma_f32_32x32x16_f16(va0, pb[ks], o0, 0,0,0);
            o1 = __builtin_amdgcn_mfma_f32_32x32x16_f16(va1, pb[ks], o1, 0,0,0);
        }
        __builtin_amdgcn_s_setprio(0);
    };

    f16x8 qmE[4], qmO[4];
    f32x16 stA[2], stB[2];

    // prologue: qm(0),qm(1) + epoch-0 tiles (quarters 0,1)
    QMLOAD(0, qmE);
    QMLOAD(1, qmO);
    STAGE(0); STAGE(1);

    #define VMW(n) asm volatile("s_waitcnt vmcnt(" #n ")" ::: "memory")

    // one barrier per 128-key epoch, at epoch END.
    // Epoch e: stage tiles 2e+2,2e+3 (other buffer pair), QK both current
    // tiles before any softmax (MFMA pipe loaded while SM runs), then
    // SMPV both; qm refilled right after its consumer.
    // vmcnt at epoch end: younger-than-stages = 8 qm refills -> VMW(8).
    VMW(0); __builtin_amdgcn_s_barrier();
    for (int e = 0; e < 15; ++e) {
        STAGE(2*e+2); STAGE(2*e+3);
        QK(2*e,   stA);
        QK(2*e+1, stB);
        SMPV(2*e,   stA, qmE);  QMLOAD(2*e+2, qmE);
        SMPV(2*e+1, stB, qmO);  QMLOAD(2*e+3, qmO);
        VMW(8); __builtin_amdgcn_s_barrier();
    }
    // epoch 15: tiles 30,31; no further stage/refill
    QK(30, stA);
    QK(31, stB);
    SMPV(30, stA, qmE);
    SMPV(31, stB, qmO);

    #undef VMW

    // epilogue
    float s_tot = s_run + __shfl_xor(s_run, 32);
    float inv = 1.0f / s_tot;
    float* ob = out + ((size_t)b_*Lq + qW + l31)*Dq + h*HDq;
    #pragma unroll
    for (int r=0;r<16;++r) {
        int drow = (r&3) + 8*(r>>2) + 4*hi;
        ob[drow]      = o0[r]*inv;
        ob[32 + drow] = o1[r]*inv;
    }
}

extern "C" void kernel_launch(void* const* d_in, const int* in_sizes, int n_in,
                              void* d_out, int out_size, void* d_ws, size_t ws_size,
                              hipStream_t stream) {
    const float* x       = (const float*)d_in[0];
    const float* quantum = (const float*)d_in[1];
    const float* wq      = (const float*)d_in[2];
    const float* wk      = (const float*)d_in[3];
    const float* wv      = (const float*)d_in[4];
    const float* scale   = (const float*)d_in[5];
    float* out = (float*)d_out;

    f16* ws     = (f16*)d_ws;
    f16* x_h    = ws;
    f16* wq_h   = ws + 4194304;
    f16* wk_h   = ws + 5242880;
    f16* wv_h   = ws + 6291456;
    f16* q_h    = ws + 7340032;
    f16* k_h    = ws + 11534336;
    f16* vT_h   = ws + 15728640;
    f16* qm_pre = ws + 19922944;

    convert_kernel<<<1024, 256, 0, stream>>>(x, wq, wk, wv, x_h, wq_h, wk_h, wv_h);

    qkv_qm_fused_kernel<<<4864, 256, 0, stream>>>(
        x_h, wq_h, wk_h, wv_h, quantum, q_h, k_h, vT_h, qm_pre);

    dim3 g2(Bq*Hq, Lq/128);
    attn4_kernel<<<g2, 256, 0, stream>>>(q_h, k_h, vT_h, qm_pre, scale, out);
}